// Round 13
// baseline (10706.188 us; speedup 1.0000x reference)
//
#include <hip/hip_runtime.h>
#include <hip/hip_bf16.h>

typedef unsigned short u16;
typedef unsigned int u32;
typedef __attribute__((ext_vector_type(4))) float f32x4;
typedef __attribute__((ext_vector_type(4))) short short4v;  // 8B
typedef __attribute__((ext_vector_type(4))) u32 uint4v;     // 16B

#define T_TOK 16384
#define HD 1024
#define NE 8
#define MAT_ELEMS (1024*1024)
#define SCALE_F 1.0f
#define OUT_ELEMS (T_TOK*HD + T_TOK*NE)

// ws layout (32.5 MiB total)
#define WS_FLAG 0
#define WS_DBG  256
#define WS_COMB 1024                         // [T][8] f32 dense combine, 512 KiB
#define WS_HBUF 525312                       // [T][1024] bf16, 32 MiB
#define WS_NEED 34079744ull

__device__ __forceinline__ float bf2f(u16 u) {
    union { u32 i; float f; } v; v.i = ((u32)u) << 16; return v.f;
}
__device__ __forceinline__ u16 f2bf(float f) {
    __hip_bfloat16 h = __float2bfloat16(f);
    return *reinterpret_cast<u16*>(&h);
}

// ---------------- diagnostic: fill (f32) output with a code value
__global__ __launch_bounds__(256) void diag_kernel(float* __restrict__ out, int n, float v)
{
    int i = blockIdx.x * 256 + threadIdx.x;
    if (i < n) out[i] = v;
}

// ---------------- dtype detector on w_router's first 256 u16s (1 = f32, 0 = bf16)
__global__ void detect_kernel(const u16* __restrict__ wr, int* __restrict__ flag)
{
    int lane = threadIdx.x & 63;
    int sane = 0;
#pragma unroll
    for (int q = 0; q < 4; q++) {
        u16 u = wr[lane * 4 + q];
        int e = (u >> 7) & 0xFF;
        if ((e >= 100 && e <= 140) || u == 0) sane++;
    }
#pragma unroll
    for (int off = 32; off; off >>= 1) sane += __shfl_xor(sane, off);
    if (lane == 0) *flag = (sane < 210) ? 1 : 0;
}

// ---------------- router: f32 logits, softmax, top-2 -> DENSE combine[T][8]; f32 logits out
__global__ __launch_bounds__(256) void router_kernel(
    const void* __restrict__ Xraw, const void* __restrict__ Wraw,
    const int* __restrict__ flag,
    float* __restrict__ Lout, float* __restrict__ combine)
{
    int t = blockIdx.x * 4 + (threadIdx.x >> 6);
    int lane = threadIdx.x & 63;
    bool isf32 = (*flag != 0);
    float xv[16];
    if (isf32) {
        const float* xr = (const float*)Xraw + (size_t)t * HD + lane * 16;
#pragma unroll
        for (int q = 0; q < 4; q++) {
            f32x4 v = *(const f32x4*)(xr + q * 4);
#pragma unroll
            for (int j = 0; j < 4; j++) xv[q * 4 + j] = v[j];
        }
    } else {
        const u16* xr = (const u16*)Xraw + (size_t)t * HD + lane * 16;
#pragma unroll
        for (int q = 0; q < 2; q++) {
            uint4v v = *(const uint4v*)(xr + q * 8);
            const u16* p = (const u16*)&v;
#pragma unroll
            for (int j = 0; j < 8; j++) xv[q * 8 + j] = bf2f(p[j]);
        }
    }
    float acc[NE];
#pragma unroll
    for (int e = 0; e < NE; e++) acc[e] = 0.f;
#pragma unroll
    for (int j = 0; j < 16; j++) {
        float wr[NE];
        if (isf32) {
            const float* w = (const float*)Wraw + (size_t)(lane * 16 + j) * NE;
            f32x4 a = *(const f32x4*)w, b = *(const f32x4*)(w + 4);
#pragma unroll
            for (int e = 0; e < 4; e++) { wr[e] = a[e]; wr[4 + e] = b[e]; }
        } else {
            uint4v v = *(const uint4v*)((const u16*)Wraw + (size_t)(lane * 16 + j) * NE);
            const u16* p = (const u16*)&v;
#pragma unroll
            for (int e = 0; e < NE; e++) wr[e] = bf2f(p[e]);
        }
#pragma unroll
        for (int e = 0; e < NE; e++) acc[e] += xv[j] * wr[e];
    }
#pragma unroll
    for (int off = 32; off; off >>= 1)
#pragma unroll
        for (int e = 0; e < NE; e++) acc[e] += __shfl_xor(acc[e], off);

    if (lane == 0) {
        float mx = acc[0];
#pragma unroll
        for (int e = 1; e < NE; e++) mx = fmaxf(mx, acc[e]);
        float p[NE], sum = 0.f;
#pragma unroll
        for (int e = 0; e < NE; e++) { p[e] = expf(acc[e] - mx); sum += p[e]; }
        float inv = 1.f / sum;
#pragma unroll
        for (int e = 0; e < NE; e++) p[e] *= inv;
        int i1 = 0;
#pragma unroll
        for (int e = 1; e < NE; e++) if (p[e] > p[i1]) i1 = e;
        int i2 = (i1 == 0) ? 1 : 0;
#pragma unroll
        for (int e = 0; e < NE; e++) { if (e == i1 || e == i2) continue; if (p[e] > p[i2]) i2 = e; }
        float cb[NE];
#pragma unroll
        for (int e = 0; e < NE; e++) cb[e] = (e == i1) ? p[i1] : ((e == i2) ? p[i2] : 0.f);
        *(f32x4*)&combine[(size_t)t * NE]     = (f32x4){cb[0], cb[1], cb[2], cb[3]};
        *(f32x4*)&combine[(size_t)t * NE + 4] = (f32x4){cb[4], cb[5], cb[6], cb[7]};
        // logits output: FLOAT32 (the reference's output dtype)
        *(f32x4*)&Lout[(size_t)t * NE]     = (f32x4){acc[0], acc[1], acc[2], acc[3]};
        *(f32x4*)&Lout[(size_t)t * NE + 4] = (f32x4){acc[4], acc[5], acc[6], acc[7]};
    }
}

// wave-uniform skip: all 4 waves test the SAME 64 rows -> block-uniform verdict
__device__ __forceinline__ bool block_active(const float* combine, int m0, int cidx, int tid)
{
    if (cidx < 0) return true;
    int r = tid & 63;
    bool nz = combine[(size_t)(m0 + r) * NE + cidx] != 0.f;
    return __any(nz);
}

// ---------------- DENSE GEMM1: hbuf = silu(X@Wg)*(X@Wu), 64x64 tile, BK=32, f32 LDS/accum.
__global__ __launch_bounds__(256) void gemm1_valu(
    const void* __restrict__ Xraw,
    const void* __restrict__ WGraw, const void* __restrict__ WUraw, int eidx,
    u16* __restrict__ hbuf, const float* __restrict__ combine,
    const int* __restrict__ flag, int cidx)
{
    int m0 = blockIdx.y * 64;
    int tid = threadIdx.x;
    if (!block_active(combine, m0, cidx, tid)) return;
    int n0 = blockIdx.x * 64;
    bool isf32 = (*flag != 0);

    __shared__ __align__(16) float As[32][68];
    __shared__ __align__(16) float Bg[32][68];
    __shared__ __align__(16) float Bu[32][68];

    int lm = tid & 63;
    int kseg = (tid >> 6) << 3;
    size_t arow = (size_t)(m0 + lm);
    int bk = tid >> 3;
    int nseg = (tid & 7) << 3;

    const float* Xf = (const float*)Xraw;
    const u16*   Xb = (const u16*)Xraw;
    const float* WGf = (const float*)WGraw + (size_t)eidx * MAT_ELEMS;
    const u16*   WGb = (const u16*)WGraw + (size_t)eidx * MAT_ELEMS;
    const float* WUf = (const float*)WUraw + (size_t)eidx * MAT_ELEMS;
    const u16*   WUb = (const u16*)WUraw + (size_t)eidx * MAT_ELEMS;

    int tm = (tid >> 4) << 2;
    int tn = (tid & 15) << 2;
    float accg[4][4] = {}, accu[4][4] = {};

    for (int kb = 0; kb < HD; kb += 32) {
        __syncthreads();
        float av[8];
        if (isf32) {
            const float* s = Xf + arow * HD + kb + kseg;
            f32x4 x0 = *(const f32x4*)s, x1 = *(const f32x4*)(s + 4);
#pragma unroll
            for (int e = 0; e < 4; e++) { av[e] = x0[e]; av[4 + e] = x1[e]; }
        } else {
            uint4v v = *(const uint4v*)(Xb + arow * HD + kb + kseg);
            const u16* p = (const u16*)&v;
#pragma unroll
            for (int e = 0; e < 8; e++) av[e] = bf2f(p[e]);
        }
#pragma unroll
        for (int e = 0; e < 8; e++) As[kseg + e][lm] = av[e];
        size_t boff = (size_t)(kb + bk) * HD + n0 + nseg;
        float bg[8], bu[8];
        if (isf32) {
            f32x4 g0 = *(const f32x4*)(WGf + boff), g1 = *(const f32x4*)(WGf + boff + 4);
            f32x4 u0 = *(const f32x4*)(WUf + boff), u1 = *(const f32x4*)(WUf + boff + 4);
#pragma unroll
            for (int e = 0; e < 4; e++) { bg[e] = g0[e]; bg[4+e] = g1[e]; bu[e] = u0[e]; bu[4+e] = u1[e]; }
        } else {
            uint4v gv = *(const uint4v*)(WGb + boff);
            uint4v uv = *(const uint4v*)(WUb + boff);
            const u16* gp = (const u16*)&gv; const u16* up = (const u16*)&uv;
#pragma unroll
            for (int e = 0; e < 8; e++) { bg[e] = bf2f(gp[e]); bu[e] = bf2f(up[e]); }
        }
        *(f32x4*)&Bg[bk][nseg]     = (f32x4){bg[0], bg[1], bg[2], bg[3]};
        *(f32x4*)&Bg[bk][nseg + 4] = (f32x4){bg[4], bg[5], bg[6], bg[7]};
        *(f32x4*)&Bu[bk][nseg]     = (f32x4){bu[0], bu[1], bu[2], bu[3]};
        *(f32x4*)&Bu[bk][nseg + 4] = (f32x4){bu[4], bu[5], bu[6], bu[7]};
        __syncthreads();
#pragma unroll 4
        for (int k = 0; k < 32; k++) {
            f32x4 a = *(const f32x4*)&As[k][tm];
            f32x4 g = *(const f32x4*)&Bg[k][tn];
            f32x4 u = *(const f32x4*)&Bu[k][tn];
#pragma unroll
            for (int i = 0; i < 4; i++)
#pragma unroll
                for (int j = 0; j < 4; j++) {
                    accg[i][j] += a[i] * g[j];
                    accu[i][j] += a[i] * u[j];
                }
        }
    }
#pragma unroll
    for (int i = 0; i < 4; i++) {
        int grow = m0 + tm + i;
        u16 hv[4];
#pragma unroll
        for (int j = 0; j < 4; j++) {
            float g = accg[i][j], u = accu[i][j];
            float s = g / (1.f + __expf(-g));   // silu
            hv[j] = f2bf(s * u);
        }
        *(short4v*)&hbuf[(size_t)grow * HD + n0 + tn] = *(short4v*)hv;
    }
}

// ---------------- DENSE GEMM2: y = hbuf @ Wd; FLOAT32 output.
// cidx<0 -> out = y (shared); cidx>=0 -> out += SCALE * combine[t][cidx] * y
__global__ __launch_bounds__(256) void gemm2_valu(
    const u16* __restrict__ hbuf,
    const void* __restrict__ WDraw, int eidx,
    float* __restrict__ out, const float* __restrict__ combine,
    const int* __restrict__ flag, int cidx)
{
    int m0 = blockIdx.y * 64;
    int tid = threadIdx.x;
    if (!block_active(combine, m0, cidx, tid)) return;
    int n0 = blockIdx.x * 64;
    bool isf32 = (*flag != 0);

    __shared__ __align__(16) float As[32][68];
    __shared__ __align__(16) float Bd[32][68];

    int lm = tid & 63;
    int kseg = (tid >> 6) << 3;
    size_t arow = (size_t)(m0 + lm);
    int bk = tid >> 3;
    int nseg = (tid & 7) << 3;

    const float* WDf = (const float*)WDraw + (size_t)eidx * MAT_ELEMS;
    const u16*   WDb = (const u16*)WDraw + (size_t)eidx * MAT_ELEMS;

    int tm = (tid >> 4) << 2;
    int tn = (tid & 15) << 2;
    float acc[4][4] = {};

    for (int kb = 0; kb < HD; kb += 32) {
        __syncthreads();
        uint4v v = *(const uint4v*)(hbuf + arow * HD + kb + kseg);
        const u16* p = (const u16*)&v;
#pragma unroll
        for (int e = 0; e < 8; e++) As[kseg + e][lm] = bf2f(p[e]);
        size_t boff = (size_t)(kb + bk) * HD + n0 + nseg;
        float bd[8];
        if (isf32) {
            f32x4 d0 = *(const f32x4*)(WDf + boff), d1 = *(const f32x4*)(WDf + boff + 4);
#pragma unroll
            for (int e = 0; e < 4; e++) { bd[e] = d0[e]; bd[4 + e] = d1[e]; }
        } else {
            uint4v dv = *(const uint4v*)(WDb + boff);
            const u16* dp = (const u16*)&dv;
#pragma unroll
            for (int e = 0; e < 8; e++) bd[e] = bf2f(dp[e]);
        }
        *(f32x4*)&Bd[bk][nseg]     = (f32x4){bd[0], bd[1], bd[2], bd[3]};
        *(f32x4*)&Bd[bk][nseg + 4] = (f32x4){bd[4], bd[5], bd[6], bd[7]};
        __syncthreads();
#pragma unroll 4
        for (int k = 0; k < 32; k++) {
            f32x4 a = *(const f32x4*)&As[k][tm];
            f32x4 d = *(const f32x4*)&Bd[k][tn];
#pragma unroll
            for (int i = 0; i < 4; i++)
#pragma unroll
                for (int j = 0; j < 4; j++) acc[i][j] += a[i] * d[j];
        }
    }
#pragma unroll
    for (int i = 0; i < 4; i++) {
        int s = m0 + tm + i;
        float* op = &out[(size_t)s * HD + n0 + tn];
        if (cidx < 0) {
            *(f32x4*)op = (f32x4){acc[i][0], acc[i][1], acc[i][2], acc[i][3]};
        } else {
            float w = SCALE_F * combine[(size_t)s * NE + cidx];
            if (w != 0.f) {
                f32x4 ov = *(const f32x4*)op;
#pragma unroll
                for (int j = 0; j < 4; j++) ov[j] += w * acc[i][j];
                *(f32x4*)op = ov;
            }
        }
    }
}

extern "C" void kernel_launch(void* const* d_in, const int* in_sizes, int n_in,
                              void* d_out, int out_size, void* d_ws, size_t ws_size,
                              hipStream_t stream) {
    float* out  = (float*)d_out;                       // FLOAT32 output (ref dtype)
    float* lout = out + (size_t)T_TOK * HD;            // logits tail, f32

    // guard: output layout assumption
    if (out_size != OUT_ELEMS) {
        diag_kernel<<<dim3((out_size + 255) / 256), 256, 0, stream>>>(out, out_size, 230.f);
        return;
    }
    // guard: full 8-entry in_sizes signature (dict order vs alphabetical)
    const int SZ_X = T_TOK * HD, SZ_R = HD * NE, SZ_S = MAT_ELEMS, SZ_E = NE * MAT_ELEMS;
    const int dictSig[8] = {SZ_X, SZ_R, SZ_S, SZ_S, SZ_S, SZ_E, SZ_E, SZ_E};
    const int alphSig[8] = {SZ_X, SZ_E, SZ_E, SZ_R, SZ_S, SZ_S, SZ_S, SZ_E};
    bool isDict = (n_in == 8), isAlph = (n_in == 8);
    for (int i = 0; i < 8 && n_in == 8; i++) {
        if (in_sizes[i] != dictSig[i]) isDict = false;
        if (in_sizes[i] != alphSig[i]) isAlph = false;
    }
    const void *X, *Wr, *shg, *shu, *shd, *wg, *wu, *wd;
    if (isDict) {
        X = d_in[0]; Wr = d_in[1]; shg = d_in[2]; shu = d_in[3]; shd = d_in[4];
        wg = d_in[5]; wu = d_in[6]; wd = d_in[7];
    } else if (isAlph) {
        X = d_in[0]; wd = d_in[1]; wg = d_in[2]; Wr = d_in[3];
        shd = d_in[4]; shg = d_in[5]; shu = d_in[6]; wu = d_in[7];
    } else {
        diag_kernel<<<dim3((out_size + 255) / 256), 256, 0, stream>>>(out, out_size, 240.f);
        return;
    }
    if (ws_size < WS_NEED) {
        diag_kernel<<<dim3((out_size + 255) / 256), 256, 0, stream>>>(
            out, out_size, (float)(ws_size >> 20));
        return;
    }

    char* ws = (char*)d_ws;
    int*   flag    = (int*)(ws + WS_FLAG);
    float* combine = (float*)(ws + WS_COMB);   // [T][8] dense weights
    u16*   hbuf    = (u16*)(ws + WS_HBUF);     // [T][1024] bf16

    detect_kernel<<<dim3(1), 64, 0, stream>>>((const u16*)Wr, flag);
    router_kernel<<<dim3(T_TOK / 4), 256, 0, stream>>>(X, Wr, flag, lout, combine);

    // shared expert: out = swiglu(X; shg, shu, shd)   (dense, overwrite)
    gemm1_valu<<<dim3(16, 256), 256, 0, stream>>>(X, shg, shu, 0, hbuf, combine, flag, -1);
    gemm2_valu<<<dim3(16, 256), 256, 0, stream>>>(hbuf, shd, 0, out, combine, flag, -1);

    // routed experts, reference-dense with zero-weight block skip: out += combine[t][e]*y_e
    for (int e = 0; e < NE; e++) {
        gemm1_valu<<<dim3(16, 256), 256, 0, stream>>>(X, wg, wu, e, hbuf, combine, flag, e);
        gemm2_valu<<<dim3(16, 256), 256, 0, stream>>>(hbuf, wd, e, out, combine, flag, e);
    }
}

// Round 14
// 1725.116 us; speedup vs baseline: 6.2061x; 6.2061x over previous
//
#include <hip/hip_runtime.h>
#include <hip/hip_bf16.h>

typedef unsigned short u16;
typedef unsigned int u32;
typedef __attribute__((ext_vector_type(8))) short short8v;   // 8 bf16 = 16B MFMA A/B frag
typedef __attribute__((ext_vector_type(4))) float f32x4;
typedef __attribute__((ext_vector_type(4))) u32 uint4v;      // 16B

#define T_TOK 16384
#define HD 1024
#define NE 8
#define NB 16
#define MAT_ELEMS (1024*1024)
#define SCALE_F 1.0f
#define OUT_ELEMS (T_TOK*HD + T_TOK*NE)

// ws layout (39.1 MiB total; proven ws_size >= 49.4 MiB from round 7 guard)
#define WS_FLAG    0
#define WS_CNT     256
#define WS_INVW    512                        // [T][2] f32
#define WS_TOKMAP  131584                     // [16][T] int
#define WS_WT      1180160                    // 3 x 1M bf16 (gate^T, up^T, down^T)
#define WS_HBUF    7471616                    // [16384][1024] bf16
#define WS_NEED    41026048ull

__device__ __forceinline__ float bf2f(u16 u) {
    union { u32 i; float f; } v; v.i = ((u32)u) << 16; return v.f;
}
__device__ __forceinline__ u16 f2bf(float f) {
    __hip_bfloat16 h = __float2bfloat16(f);
    return *reinterpret_cast<u16*>(&h);
}

__global__ __launch_bounds__(256) void diag_kernel(float* __restrict__ out, int n, float v)
{
    int i = blockIdx.x * 256 + threadIdx.x;
    if (i < n) out[i] = v;
}

__global__ void zero_kernel(int* __restrict__ cnt)
{
    if (threadIdx.x < NB) cnt[threadIdx.x] = 0;
}

// dtype detector on w_router's first 256 u16s (1 = f32, 0 = bf16)
__global__ void detect_kernel(const u16* __restrict__ wr, int* __restrict__ flag)
{
    int lane = threadIdx.x & 63;
    int sane = 0;
#pragma unroll
    for (int q = 0; q < 4; q++) {
        u16 u = wr[lane * 4 + q];
        int e = (u >> 7) & 0xFF;
        if ((e >= 100 && e <= 140) || u == 0) sane++;
    }
#pragma unroll
    for (int off = 32; off; off >>= 1) sane += __shfl_xor(sane, off);
    if (lane == 0) *flag = (sane < 210) ? 1 : 0;
}

// ---------------- router (round-10-verified bucketed version, f32 logits out)
__global__ __launch_bounds__(256) void router_kernel(
    const void* __restrict__ Xraw, const void* __restrict__ Wraw,
    const int* __restrict__ flag,
    float* __restrict__ Lout, int* __restrict__ cnt,
    int* __restrict__ tokmap, float* __restrict__ invw)
{
    int t = blockIdx.x * 4 + (threadIdx.x >> 6);
    int lane = threadIdx.x & 63;
    bool isf32 = (*flag != 0);
    float xv[16];
    if (isf32) {
        const float* xr = (const float*)Xraw + (size_t)t * HD + lane * 16;
#pragma unroll
        for (int q = 0; q < 4; q++) {
            f32x4 v = *(const f32x4*)(xr + q * 4);
#pragma unroll
            for (int j = 0; j < 4; j++) xv[q * 4 + j] = v[j];
        }
    } else {
        const u16* xr = (const u16*)Xraw + (size_t)t * HD + lane * 16;
#pragma unroll
        for (int q = 0; q < 2; q++) {
            uint4v v = *(const uint4v*)(xr + q * 8);
            const u16* p = (const u16*)&v;
#pragma unroll
            for (int j = 0; j < 8; j++) xv[q * 8 + j] = bf2f(p[j]);
        }
    }
    float acc[NE];
#pragma unroll
    for (int e = 0; e < NE; e++) acc[e] = 0.f;
#pragma unroll
    for (int j = 0; j < 16; j++) {
        float wr[NE];
        if (isf32) {
            const float* w = (const float*)Wraw + (size_t)(lane * 16 + j) * NE;
            f32x4 a = *(const f32x4*)w, b = *(const f32x4*)(w + 4);
#pragma unroll
            for (int e = 0; e < 4; e++) { wr[e] = a[e]; wr[4 + e] = b[e]; }
        } else {
            uint4v v = *(const uint4v*)((const u16*)Wraw + (size_t)(lane * 16 + j) * NE);
            const u16* p = (const u16*)&v;
#pragma unroll
            for (int e = 0; e < NE; e++) wr[e] = bf2f(p[e]);
        }
#pragma unroll
        for (int e = 0; e < NE; e++) acc[e] += xv[j] * wr[e];
    }
#pragma unroll
    for (int off = 32; off; off >>= 1)
#pragma unroll
        for (int e = 0; e < NE; e++) acc[e] += __shfl_xor(acc[e], off);

    if (lane == 0) {
        float mx = acc[0];
#pragma unroll
        for (int e = 1; e < NE; e++) mx = fmaxf(mx, acc[e]);
        float p[NE], sum = 0.f;
#pragma unroll
        for (int e = 0; e < NE; e++) { p[e] = expf(acc[e] - mx); sum += p[e]; }
        float inv = 1.f / sum;
#pragma unroll
        for (int e = 0; e < NE; e++) p[e] *= inv;
        int i1 = 0;
#pragma unroll
        for (int e = 1; e < NE; e++) if (p[e] > p[i1]) i1 = e;
        int i2 = (i1 == 0) ? 1 : 0;
#pragma unroll
        for (int e = 0; e < NE; e++) { if (e == i1 || e == i2) continue; if (p[e] > p[i2]) i2 = e; }
        // f32 logits (output dtype)
        *(f32x4*)&Lout[(size_t)t * NE]     = (f32x4){acc[0], acc[1], acc[2], acc[3]};
        *(f32x4*)&Lout[(size_t)t * NE + 4] = (f32x4){acc[4], acc[5], acc[6], acc[7]};
        int b1 = i1 * 2 + 0;
        int p1 = atomicAdd(&cnt[b1], 1);
        tokmap[b1 * T_TOK + p1] = t;
        invw[t * 2 + 0] = p[i1];
        int b2 = i2 * 2 + 1;
        int p2 = atomicAdd(&cnt[b2], 1);
        tokmap[b2 * T_TOK + p2] = t;
        invw[t * 2 + 1] = p[i2];
    }
}

// ---------------- transpose+convert one expert's 3 matrices -> wT [n][k] bf16
__global__ __launch_bounds__(256) void transpose3_kernel(
    const void* __restrict__ gsrc, const void* __restrict__ usrc, const void* __restrict__ dsrc,
    int expertIdx, const int* __restrict__ flag,
    u16* __restrict__ wT)
{
    __shared__ u16 tile[64][66];
    int z = blockIdx.z;
    const void* srcv = (z == 0) ? gsrc : (z == 1) ? usrc : dsrc;
    size_t base = (size_t)expertIdx * MAT_ELEMS;
    u16* dst = wT + (size_t)z * MAT_ELEMS;
    int h0 = blockIdx.x * 64;
    int n0 = blockIdx.y * 64;
    int tid = threadIdx.x;
    bool isf32 = (*flag != 0);
#pragma unroll
    for (int i = 0; i < 2; i++) {
        int v = tid + i * 256;
        int row = v >> 3, c8 = v & 7;
        size_t idx = base + (size_t)(h0 + row) * HD + n0 + c8 * 8;
        u16 pv[8];
        if (isf32) {
            const float* s = (const float*)srcv + idx;
            f32x4 a = *(const f32x4*)s;
            f32x4 b = *(const f32x4*)(s + 4);
#pragma unroll
            for (int j = 0; j < 4; j++) { pv[j] = f2bf(a[j]); pv[4 + j] = f2bf(b[j]); }
        } else {
            *(uint4v*)pv = *(const uint4v*)((const u16*)srcv + idx);
        }
#pragma unroll
        for (int j = 0; j < 8; j++) tile[c8 * 8 + j][row] = pv[j];
    }
    __syncthreads();
#pragma unroll
    for (int i = 0; i < 2; i++) {
        int v = tid + i * 256;
        int row = v >> 3, c8 = v & 7;
        u16 pv[8];
#pragma unroll
        for (int j = 0; j < 8; j++) pv[j] = tile[row][c8 * 8 + j];
        *(uint4v*)&dst[(size_t)(n0 + row) * HD + h0 + c8 * 8] = *(uint4v*)pv;
    }
}

// ---------------- MFMA GEMM1: h = silu(X@Wg)*(X@Wu) -> hbuf (bf16, compacted rows)
// bucketBase < 0: shared (z grid 1, identity rows). else bucket = bucketBase + z, hbase = z*8192.
__global__ __launch_bounds__(256) void gemm1_mfma(
    const void* __restrict__ Xraw,
    const u16* __restrict__ Wg, const u16* __restrict__ Wu,
    u16* __restrict__ hbuf,
    const int* __restrict__ cnt, const int* __restrict__ tokmap,
    const int* __restrict__ flag, int bucketBase)
{
    int z = blockIdx.z;
    int bucket = (bucketBase < 0) ? -1 : (bucketBase + z);
    int active = (bucket < 0) ? T_TOK : cnt[bucket];
    int rb = blockIdx.y;
    if (rb * 128 >= active) return;
    int tid = threadIdx.x;
    bool isf32 = (*flag != 0);
    int hbase = z * 8192;

    int r = tid & 127;
    int h = tid >> 7;                        // k-half (0/1): covers k = h*8 + q*16
    int grow = rb * 128 + r;
    int srow = (grow < active) ? grow : (active - 1);
    size_t arow = (bucket < 0) ? (size_t)srow : (size_t)tokmap[bucket * T_TOK + srow];

    const float* af = (const float*)Xraw + arow * HD + h * 8;
    const u16*   ab = (const u16*)Xraw + arow * HD + h * 8;
    size_t woff = (size_t)(blockIdx.x * 128 + r) * HD + h * 8;
    const u16* w0p = Wg + woff;
    const u16* w1p = Wu + woff;

    __shared__ short lds[17408];   // staging A/B0/B1 (3x4096); epilogue 128x136
    short* ldsA  = lds;
    short* ldsB0 = lds + 4096;
    short* ldsB1 = lds + 8192;

    f32x4 acc0[4][4], acc1[4][4];
#pragma unroll
    for (int i = 0; i < 4; i++)
#pragma unroll
        for (int j = 0; j < 4; j++) {
            acc0[i][j] = (f32x4){0.f, 0.f, 0.f, 0.f};
            acc1[i][j] = (f32x4){0.f, 0.f, 0.f, 0.f};
        }

    int lane = tid & 63;
    int wid = tid >> 6;
    int wm = (wid >> 1) * 64, wn = (wid & 1) * 64;
    int lg = lane >> 4, lm = lane & 15;

    auto loadA = [&](int ko) -> uint4v {
        if (isf32) {
            f32x4 x0 = *(const f32x4*)(af + ko);
            f32x4 x1 = *(const f32x4*)(af + ko + 4);
            u16 t[8];
#pragma unroll
            for (int j = 0; j < 4; j++) { t[j] = f2bf(x0[j]); t[4 + j] = f2bf(x1[j]); }
            return *(uint4v*)t;
        }
        return *(const uint4v*)(ab + ko);
    };

    uint4v ra[2], rb0[2], rb1[2];
#pragma unroll
    for (int q = 0; q < 2; q++) {
        ra[q]  = loadA(q * 16);
        rb0[q] = *(const uint4v*)(w0p + q * 16);
        rb1[q] = *(const uint4v*)(w1p + q * 16);
    }

    for (int kk = 0; kk < 32; ++kk) {
        __syncthreads();
#pragma unroll
        for (int q = 0; q < 2; q++) {
            *(uint4v*)&ldsA[(size_t)(q * 256 + tid) * 8]  = ra[q];
            *(uint4v*)&ldsB0[(size_t)(q * 256 + tid) * 8] = rb0[q];
            *(uint4v*)&ldsB1[(size_t)(q * 256 + tid) * 8] = rb1[q];
        }
        if (kk + 1 < 32) {
            int ko = (kk + 1) * 32;
#pragma unroll
            for (int q = 0; q < 2; q++) {
                ra[q]  = loadA(ko + q * 16);
                rb0[q] = *(const uint4v*)(w0p + ko + q * 16);
                rb1[q] = *(const uint4v*)(w1p + ko + q * 16);
            }
        }
        __syncthreads();
        short8v afr[4], b0f[4], b1f[4];
#pragma unroll
        for (int f = 0; f < 4; f++) {
            afr[f] = *(const short8v*)&ldsA[(size_t)(lg * 128 + wm + f * 16 + lm) * 8];
            b0f[f] = *(const short8v*)&ldsB0[(size_t)(lg * 128 + wn + f * 16 + lm) * 8];
            b1f[f] = *(const short8v*)&ldsB1[(size_t)(lg * 128 + wn + f * 16 + lm) * 8];
        }
#pragma unroll
        for (int i = 0; i < 4; i++)
#pragma unroll
            for (int j = 0; j < 4; j++) {
                acc0[i][j] = __builtin_amdgcn_mfma_f32_16x16x32_bf16(afr[i], b0f[j], acc0[i][j], 0, 0, 0);
                acc1[i][j] = __builtin_amdgcn_mfma_f32_16x16x32_bf16(afr[i], b1f[j], acc1[i][j], 0, 0, 0);
            }
    }

    __syncthreads();
#pragma unroll
    for (int i = 0; i < 4; i++)
#pragma unroll
        for (int j = 0; j < 4; j++)
#pragma unroll
            for (int rr = 0; rr < 4; rr++) {
                int m = wm + i * 16 + (lane >> 4) * 4 + rr;
                int n = wn + j * 16 + lm;
                float g = acc0[i][j][rr];
                float u = acc1[i][j][rr];
                float sg = g / (1.f + __expf(-g));    // silu
                lds[m * 136 + n] = (short)f2bf(sg * u);
            }
    __syncthreads();
#pragma unroll
    for (int i = 0; i < 8; i++) {
        int s0 = tid + i * 256;
        int row = s0 >> 4;
        int c8 = s0 & 15;
        if (rb * 128 + row < active) {
            uint4v v = *(const uint4v*)&lds[row * 136 + c8 * 8];
            *(uint4v*)&hbuf[(size_t)(hbase + rb * 128 + row) * HD + blockIdx.x * 128 + c8 * 8] = v;
        }
    }
}

// ---------------- MFMA GEMM2: y = h @ Wd, f32 out with fused combine.
// bucketBase < 0: out[row] = y (shared). else out[tokmap[...]] += SCALE*invw*y.
__global__ __launch_bounds__(256) void gemm2_mfma(
    const u16* __restrict__ hbuf, const u16* __restrict__ Wd,
    float* __restrict__ out,
    const int* __restrict__ cnt, const int* __restrict__ tokmap,
    const float* __restrict__ invw, int bucketBase)
{
    int z = blockIdx.z;
    int bucket = (bucketBase < 0) ? -1 : (bucketBase + z);
    int active = (bucket < 0) ? T_TOK : cnt[bucket];
    int rb = blockIdx.y;
    if (rb * 128 >= active) return;
    int tid = threadIdx.x;
    int hbase = z * 8192;

    int r = tid & 127;
    int h = tid >> 7;
    int grow = rb * 128 + r;
    int srow = (grow < active) ? grow : (active - 1);
    const u16* aptr = hbuf + (size_t)(hbase + srow) * HD + h * 8;
    size_t woff = (size_t)(blockIdx.x * 128 + r) * HD + h * 8;
    const u16* w0p = Wd + woff;

    __shared__ short lds[8192];    // staging A/B (2x4096)
    short* ldsA  = lds;
    short* ldsB0 = lds + 4096;

    f32x4 acc[4][4];
#pragma unroll
    for (int i = 0; i < 4; i++)
#pragma unroll
        for (int j = 0; j < 4; j++) acc[i][j] = (f32x4){0.f, 0.f, 0.f, 0.f};

    int lane = tid & 63;
    int wid = tid >> 6;
    int wm = (wid >> 1) * 64, wn = (wid & 1) * 64;
    int lg = lane >> 4, lm = lane & 15;

    uint4v ra[2], rb0[2];
#pragma unroll
    for (int q = 0; q < 2; q++) {
        ra[q]  = *(const uint4v*)(aptr + q * 16);
        rb0[q] = *(const uint4v*)(w0p + q * 16);
    }

    for (int kk = 0; kk < 32; ++kk) {
        __syncthreads();
#pragma unroll
        for (int q = 0; q < 2; q++) {
            *(uint4v*)&ldsA[(size_t)(q * 256 + tid) * 8]  = ra[q];
            *(uint4v*)&ldsB0[(size_t)(q * 256 + tid) * 8] = rb0[q];
        }
        if (kk + 1 < 32) {
            int ko = (kk + 1) * 32;
#pragma unroll
            for (int q = 0; q < 2; q++) {
                ra[q]  = *(const uint4v*)(aptr + ko + q * 16);
                rb0[q] = *(const uint4v*)(w0p + ko + q * 16);
            }
        }
        __syncthreads();
        short8v afr[4], b0f[4];
#pragma unroll
        for (int f = 0; f < 4; f++) {
            afr[f] = *(const short8v*)&ldsA[(size_t)(lg * 128 + wm + f * 16 + lm) * 8];
            b0f[f] = *(const short8v*)&ldsB0[(size_t)(lg * 128 + wn + f * 16 + lm) * 8];
        }
#pragma unroll
        for (int i = 0; i < 4; i++)
#pragma unroll
            for (int j = 0; j < 4; j++)
                acc[i][j] = __builtin_amdgcn_mfma_f32_16x16x32_bf16(afr[i], b0f[j], acc[i][j], 0, 0, 0);
    }

    // epilogue: direct f32 stores (no LDS repack; 16-lane 64B segments)
#pragma unroll
    for (int i = 0; i < 4; i++)
#pragma unroll
        for (int rr = 0; rr < 4; rr++) {
            int m = wm + i * 16 + (lane >> 4) * 4 + rr;
            int s = rb * 128 + m;
            if (s < active) {
                if (bucket < 0) {
                    size_t rowOff = (size_t)s * HD + blockIdx.x * 128;
#pragma unroll
                    for (int j = 0; j < 4; j++)
                        out[rowOff + wn + j * 16 + lm] = acc[i][j][rr];
                } else {
                    int t = tokmap[bucket * T_TOK + s];
                    float w = SCALE_F * invw[t * 2 + (bucket & 1)];
                    size_t rowOff = (size_t)t * HD + blockIdx.x * 128;
#pragma unroll
                    for (int j = 0; j < 4; j++)
                        out[rowOff + wn + j * 16 + lm] += w * acc[i][j][rr];
                }
            }
        }
}

extern "C" void kernel_launch(void* const* d_in, const int* in_sizes, int n_in,
                              void* d_out, int out_size, void* d_ws, size_t ws_size,
                              hipStream_t stream) {
    float* out  = (float*)d_out;
    float* lout = out + (size_t)T_TOK * HD;

    if (out_size != OUT_ELEMS) {
        diag_kernel<<<dim3((out_size + 255) / 256), 256, 0, stream>>>(out, out_size, 230.f);
        return;
    }
    const int SZ_X = T_TOK * HD, SZ_R = HD * NE, SZ_S = MAT_ELEMS, SZ_E = NE * MAT_ELEMS;
    const int dictSig[8] = {SZ_X, SZ_R, SZ_S, SZ_S, SZ_S, SZ_E, SZ_E, SZ_E};
    const int alphSig[8] = {SZ_X, SZ_E, SZ_E, SZ_R, SZ_S, SZ_S, SZ_S, SZ_E};
    bool isDict = (n_in == 8), isAlph = (n_in == 8);
    for (int i = 0; i < 8 && n_in == 8; i++) {
        if (in_sizes[i] != dictSig[i]) isDict = false;
        if (in_sizes[i] != alphSig[i]) isAlph = false;
    }
    const void *X, *Wr, *shg, *shu, *shd, *wg, *wu, *wd;
    if (isDict) {
        X = d_in[0]; Wr = d_in[1]; shg = d_in[2]; shu = d_in[3]; shd = d_in[4];
        wg = d_in[5]; wu = d_in[6]; wd = d_in[7];
    } else if (isAlph) {
        X = d_in[0]; wd = d_in[1]; wg = d_in[2]; Wr = d_in[3];
        shd = d_in[4]; shg = d_in[5]; shu = d_in[6]; wu = d_in[7];
    } else {
        diag_kernel<<<dim3((out_size + 255) / 256), 256, 0, stream>>>(out, out_size, 240.f);
        return;
    }
    if (ws_size < WS_NEED) {
        diag_kernel<<<dim3((out_size + 255) / 256), 256, 0, stream>>>(
            out, out_size, (float)(ws_size >> 20));
        return;
    }

    char* ws = (char*)d_ws;
    int*   flag   = (int*)(ws + WS_FLAG);
    int*   cnt    = (int*)(ws + WS_CNT);
    float* invw   = (float*)(ws + WS_INVW);
    int*   tokmap = (int*)(ws + WS_TOKMAP);
    u16*   wT     = (u16*)(ws + WS_WT);       // rotating: gate^T, up^T, down^T (bf16)
    u16*   hbuf   = (u16*)(ws + WS_HBUF);     // [16384][1024] bf16
    u16*   wTg = wT, *wTu = wT + MAT_ELEMS, *wTd = wT + 2ull * MAT_ELEMS;

    detect_kernel<<<dim3(1), 64, 0, stream>>>((const u16*)Wr, flag);
    zero_kernel<<<dim3(1), 64, 0, stream>>>(cnt);
    router_kernel<<<dim3(T_TOK / 4), 256, 0, stream>>>(X, Wr, flag, lout, cnt, tokmap, invw);

    // shared expert: out = swiglu(X) over all T rows
    transpose3_kernel<<<dim3(16, 16, 3), 256, 0, stream>>>(shg, shu, shd, 0, flag, wT);
    gemm1_mfma<<<dim3(8, 128, 1), 256, 0, stream>>>(X, wTg, wTu, hbuf, cnt, tokmap, flag, -1);
    gemm2_mfma<<<dim3(8, 128, 1), 256, 0, stream>>>(hbuf, wTd, out, cnt, tokmap, invw, -1);

    // routed experts: rotate weights; z = k-bucket (2 per expert); out += w*y
    for (int e = 0; e < NE; e++) {
        transpose3_kernel<<<dim3(16, 16, 3), 256, 0, stream>>>(wg, wu, wd, e, flag, wT);
        gemm1_mfma<<<dim3(8, 64, 2), 256, 0, stream>>>(X, wTg, wTu, hbuf, cnt, tokmap, flag, e * 2);
        gemm2_mfma<<<dim3(8, 64, 2), 256, 0, stream>>>(hbuf, wTd, out, cnt, tokmap, invw, e * 2);
    }
}

// Round 15
// 1406.825 us; speedup vs baseline: 7.6102x; 1.2262x over previous
//
#include <hip/hip_runtime.h>
#include <hip/hip_bf16.h>

typedef unsigned short u16;
typedef unsigned int u32;
typedef __attribute__((ext_vector_type(8))) short short8v;   // 8 bf16 = 16B MFMA A/B frag
typedef __attribute__((ext_vector_type(4))) float f32x4;
typedef __attribute__((ext_vector_type(4))) u32 uint4v;      // 16B

#define T_TOK 16384
#define HD 1024
#define NE 8
#define NB 16
#define MAT_ELEMS (1024*1024)
#define SCALE_F 1.0f
#define OUT_ELEMS (T_TOK*HD + T_TOK*NE)

// ws layout (39.2 MiB total; proven ws_size >= 49.4 MiB from round-7 guard)
#define WS_FLAG    0
#define WS_CNT     256
#define WS_INVW    512                        // [T][2] f32
#define WS_PICKS   131584                     // [T] u32 (e1 | e2<<8)
#define WS_TOKMAP  197120                     // [16][T] int
#define WS_WT      1245696                    // 3 x 1M bf16 (gate^T, up^T, down^T)
#define WS_HBUF    7537152                    // [16384][1024] bf16
#define WS_NEED    41091584ull

typedef const __attribute__((address_space(1))) u32* gas_ptr;
typedef __attribute__((address_space(3))) u32* las_ptr;

__device__ __forceinline__ void gload16(const void* g, void* l) {
    __builtin_amdgcn_global_load_lds((gas_ptr)g, (las_ptr)l, 16, 0, 0);
}

__device__ __forceinline__ float bf2f(u16 u) {
    union { u32 i; float f; } v; v.i = ((u32)u) << 16; return v.f;
}
__device__ __forceinline__ u16 f2bf(float f) {
    __hip_bfloat16 h = __float2bfloat16(f);
    return *reinterpret_cast<u16*>(&h);
}

__global__ __launch_bounds__(256) void diag_kernel(float* __restrict__ out, int n, float v)
{
    int i = blockIdx.x * 256 + threadIdx.x;
    if (i < n) out[i] = v;
}

// dtype detector on w_router's first 256 u16s (1 = f32, 0 = bf16)
__global__ void detect_kernel(const u16* __restrict__ wr, int* __restrict__ flag)
{
    int lane = threadIdx.x & 63;
    int sane = 0;
#pragma unroll
    for (int q = 0; q < 4; q++) {
        u16 u = wr[lane * 4 + q];
        int e = (u >> 7) & 0xFF;
        if ((e >= 100 && e <= 140) || u == 0) sane++;
    }
#pragma unroll
    for (int off = 32; off; off >>= 1) sane += __shfl_xor(sane, off);
    if (lane == 0) *flag = (sane < 210) ? 1 : 0;
}

// ---------------- router phase 1: verified per-token math; NO atomics.
// writes picks[t] = e1 | (e2<<8), invw[t][2], f32 logits.
__global__ __launch_bounds__(256) void router_kernel(
    const void* __restrict__ Xraw, const void* __restrict__ Wraw,
    const int* __restrict__ flag,
    float* __restrict__ Lout, u32* __restrict__ picks, float* __restrict__ invw)
{
    int t = blockIdx.x * 4 + (threadIdx.x >> 6);
    int lane = threadIdx.x & 63;
    bool isf32 = (*flag != 0);
    float xv[16];
    if (isf32) {
        const float* xr = (const float*)Xraw + (size_t)t * HD + lane * 16;
#pragma unroll
        for (int q = 0; q < 4; q++) {
            f32x4 v = *(const f32x4*)(xr + q * 4);
#pragma unroll
            for (int j = 0; j < 4; j++) xv[q * 4 + j] = v[j];
        }
    } else {
        const u16* xr = (const u16*)Xraw + (size_t)t * HD + lane * 16;
#pragma unroll
        for (int q = 0; q < 2; q++) {
            uint4v v = *(const uint4v*)(xr + q * 8);
            const u16* p = (const u16*)&v;
#pragma unroll
            for (int j = 0; j < 8; j++) xv[q * 8 + j] = bf2f(p[j]);
        }
    }
    float acc[NE];
#pragma unroll
    for (int e = 0; e < NE; e++) acc[e] = 0.f;
#pragma unroll
    for (int j = 0; j < 16; j++) {
        float wr[NE];
        if (isf32) {
            const float* w = (const float*)Wraw + (size_t)(lane * 16 + j) * NE;
            f32x4 a = *(const f32x4*)w, b = *(const f32x4*)(w + 4);
#pragma unroll
            for (int e = 0; e < 4; e++) { wr[e] = a[e]; wr[4 + e] = b[e]; }
        } else {
            uint4v v = *(const uint4v*)((const u16*)Wraw + (size_t)(lane * 16 + j) * NE);
            const u16* p = (const u16*)&v;
#pragma unroll
            for (int e = 0; e < NE; e++) wr[e] = bf2f(p[e]);
        }
#pragma unroll
        for (int e = 0; e < NE; e++) acc[e] += xv[j] * wr[e];
    }
#pragma unroll
    for (int off = 32; off; off >>= 1)
#pragma unroll
        for (int e = 0; e < NE; e++) acc[e] += __shfl_xor(acc[e], off);

    if (lane == 0) {
        float mx = acc[0];
#pragma unroll
        for (int e = 1; e < NE; e++) mx = fmaxf(mx, acc[e]);
        float p[NE], sum = 0.f;
#pragma unroll
        for (int e = 0; e < NE; e++) { p[e] = expf(acc[e] - mx); sum += p[e]; }
        float inv = 1.f / sum;
#pragma unroll
        for (int e = 0; e < NE; e++) p[e] *= inv;
        int i1 = 0;
#pragma unroll
        for (int e = 1; e < NE; e++) if (p[e] > p[i1]) i1 = e;
        int i2 = (i1 == 0) ? 1 : 0;
#pragma unroll
        for (int e = 0; e < NE; e++) { if (e == i1 || e == i2) continue; if (p[e] > p[i2]) i2 = e; }
        *(f32x4*)&Lout[(size_t)t * NE]     = (f32x4){acc[0], acc[1], acc[2], acc[3]};
        *(f32x4*)&Lout[(size_t)t * NE + 4] = (f32x4){acc[4], acc[5], acc[6], acc[7]};
        picks[t] = (u32)i1 | ((u32)i2 << 8);
        invw[t * 2 + 0] = p[i1];
        invw[t * 2 + 1] = p[i2];
    }
}

// ---------------- router phase 2: deterministic stable compaction, 1 block per bucket
__global__ __launch_bounds__(256) void compact_kernel(
    const u32* __restrict__ picks, int* __restrict__ cnt, int* __restrict__ tokmap)
{
    __shared__ int wtot[4];
    int b = blockIdx.x;
    int e = b >> 1;
    bool k1 = (b & 1) != 0;
    int tid = threadIdx.x, lane = tid & 63, wid = tid >> 6;
    int base = 0;
    for (int t0 = 0; t0 < T_TOK; t0 += 256) {
        int t = t0 + tid;
        u32 pk = picks[t];
        int pe = k1 ? (int)((pk >> 8) & 0xFF) : (int)(pk & 0xFF);
        bool f = (pe == e);
        unsigned long long m = __ballot(f);
        int off = (int)__popcll(m & ((1ull << lane) - 1ull));
        if (lane == 0) wtot[wid] = (int)__popcll(m);
        __syncthreads();
        int wbase = 0;
#pragma unroll
        for (int w = 0; w < 4; w++) wbase += (w < wid) ? wtot[w] : 0;
        int tot = wtot[0] + wtot[1] + wtot[2] + wtot[3];
        if (f) tokmap[b * T_TOK + base + wbase + off] = t;
        base += tot;
        __syncthreads();
    }
    if (tid == 0) cnt[b] = base;
}

// ---------------- transpose+convert one expert's 3 matrices -> wT [n][k] bf16
__global__ __launch_bounds__(256) void transpose3_kernel(
    const void* __restrict__ gsrc, const void* __restrict__ usrc, const void* __restrict__ dsrc,
    int expertIdx, const int* __restrict__ flag,
    u16* __restrict__ wT)
{
    __shared__ u16 tile[64][66];
    int z = blockIdx.z;
    const void* srcv = (z == 0) ? gsrc : (z == 1) ? usrc : dsrc;
    size_t base = (size_t)expertIdx * MAT_ELEMS;
    u16* dst = wT + (size_t)z * MAT_ELEMS;
    int h0 = blockIdx.x * 64;
    int n0 = blockIdx.y * 64;
    int tid = threadIdx.x;
    bool isf32 = (*flag != 0);
#pragma unroll
    for (int i = 0; i < 2; i++) {
        int v = tid + i * 256;
        int row = v >> 3, c8 = v & 7;
        size_t idx = base + (size_t)(h0 + row) * HD + n0 + c8 * 8;
        u16 pv[8];
        if (isf32) {
            const float* s = (const float*)srcv + idx;
            f32x4 a = *(const f32x4*)s;
            f32x4 b = *(const f32x4*)(s + 4);
#pragma unroll
            for (int j = 0; j < 4; j++) { pv[j] = f2bf(a[j]); pv[4 + j] = f2bf(b[j]); }
        } else {
            *(uint4v*)pv = *(const uint4v*)((const u16*)srcv + idx);
        }
#pragma unroll
        for (int j = 0; j < 8; j++) tile[c8 * 8 + j][row] = pv[j];
    }
    __syncthreads();
#pragma unroll
    for (int i = 0; i < 2; i++) {
        int v = tid + i * 256;
        int row = v >> 3, c8 = v & 7;
        u16 pv[8];
#pragma unroll
        for (int j = 0; j < 8; j++) pv[j] = tile[row][c8 * 8 + j];
        *(uint4v*)&dst[(size_t)(n0 + row) * HD + h0 + c8 * 8] = *(uint4v*)pv;
    }
}

// ---------------- MFMA GEMM1: h = silu(X@Wg)*(X@Wu) -> hbuf (bf16, compacted rows)
// A: reg-staged f32->bf16 cvt (prefetch under MFMA). B0/B1: global_load_lds width 16.
__global__ __launch_bounds__(256) void gemm1_mfma(
    const void* __restrict__ Xraw,
    const u16* __restrict__ Wg, const u16* __restrict__ Wu,
    u16* __restrict__ hbuf,
    const int* __restrict__ cnt, const int* __restrict__ tokmap,
    const int* __restrict__ flag, int bucketBase)
{
    int z = blockIdx.z;
    int bucket = (bucketBase < 0) ? -1 : (bucketBase + z);
    int active = (bucket < 0) ? T_TOK : cnt[bucket];
    int rb = blockIdx.y;
    if (rb * 128 >= active) return;
    int tid = threadIdx.x;
    bool isf32 = (*flag != 0);
    int hbase = z * 8192;

    int r = tid & 127;
    int h = tid >> 7;                        // k-half (0/1)
    int grow = rb * 128 + r;
    int srow = (grow < active) ? grow : (active - 1);
    size_t arow = (bucket < 0) ? (size_t)srow : (size_t)tokmap[bucket * T_TOK + srow];

    const float* af = (const float*)Xraw + arow * HD + h * 8;
    const u16*   ab = (const u16*)Xraw + arow * HD + h * 8;
    size_t woff = (size_t)(blockIdx.x * 128 + r) * HD + h * 8;
    const u16* w0p = Wg + woff;
    const u16* w1p = Wu + woff;

    __shared__ short lds[17408];   // staging A/B0/B1 (3x4096 shorts); epilogue 128x136
    short* ldsA  = lds;
    short* ldsB0 = lds + 4096;
    short* ldsB1 = lds + 8192;

    f32x4 acc0[4][4], acc1[4][4];
#pragma unroll
    for (int i = 0; i < 4; i++)
#pragma unroll
        for (int j = 0; j < 4; j++) {
            acc0[i][j] = (f32x4){0.f, 0.f, 0.f, 0.f};
            acc1[i][j] = (f32x4){0.f, 0.f, 0.f, 0.f};
        }

    int lane = tid & 63;
    int wid = tid >> 6;
    int wm = (wid >> 1) * 64, wn = (wid & 1) * 64;
    int lg = lane >> 4, lm = lane & 15;

    auto loadA = [&](int ko) -> uint4v {
        if (isf32) {
            f32x4 x0 = *(const f32x4*)(af + ko);
            f32x4 x1 = *(const f32x4*)(af + ko + 4);
            u16 t[8];
#pragma unroll
            for (int j = 0; j < 4; j++) { t[j] = f2bf(x0[j]); t[4 + j] = f2bf(x1[j]); }
            return *(uint4v*)t;
        }
        return *(const uint4v*)(ab + ko);
    };

    uint4v ra[2];
#pragma unroll
    for (int q = 0; q < 2; q++) ra[q] = loadA(q * 16);

    for (int kk = 0; kk < 32; ++kk) {
        __syncthreads();                          // LDS free from prev compute
#pragma unroll
        for (int q = 0; q < 2; q++) {
            *(uint4v*)&ldsA[(size_t)(q * 256 + tid) * 8] = ra[q];
            // B: direct global->LDS, wave-uniform dest base + lane*16
            gload16(w0p + kk * 32 + q * 16, &ldsB0[(size_t)(q * 256 + wid * 64) * 8]);
            gload16(w1p + kk * 32 + q * 16, &ldsB1[(size_t)(q * 256 + wid * 64) * 8]);
        }
        __syncthreads();                          // vmcnt(0): B landed, A written
        if (kk + 1 < 32) {                        // A-prefetch hides under MFMA
#pragma unroll
            for (int q = 0; q < 2; q++) ra[q] = loadA((kk + 1) * 32 + q * 16);
        }
        short8v afr[4], b0f[4], b1f[4];
#pragma unroll
        for (int f = 0; f < 4; f++) {
            afr[f] = *(const short8v*)&ldsA[(size_t)(lg * 128 + wm + f * 16 + lm) * 8];
            b0f[f] = *(const short8v*)&ldsB0[(size_t)(lg * 128 + wn + f * 16 + lm) * 8];
            b1f[f] = *(const short8v*)&ldsB1[(size_t)(lg * 128 + wn + f * 16 + lm) * 8];
        }
#pragma unroll
        for (int i = 0; i < 4; i++)
#pragma unroll
            for (int j = 0; j < 4; j++) {
                acc0[i][j] = __builtin_amdgcn_mfma_f32_16x16x32_bf16(afr[i], b0f[j], acc0[i][j], 0, 0, 0);
                acc1[i][j] = __builtin_amdgcn_mfma_f32_16x16x32_bf16(afr[i], b1f[j], acc1[i][j], 0, 0, 0);
            }
    }

    __syncthreads();
#pragma unroll
    for (int i = 0; i < 4; i++)
#pragma unroll
        for (int j = 0; j < 4; j++)
#pragma unroll
            for (int rr = 0; rr < 4; rr++) {
                int m = wm + i * 16 + (lane >> 4) * 4 + rr;
                int n = wn + j * 16 + lm;
                float g = acc0[i][j][rr];
                float u = acc1[i][j][rr];
                float sg = g / (1.f + __expf(-g));    // silu
                lds[m * 136 + n] = (short)f2bf(sg * u);
            }
    __syncthreads();
#pragma unroll
    for (int i = 0; i < 8; i++) {
        int s0 = tid + i * 256;
        int row = s0 >> 4;
        int c8 = s0 & 15;
        if (rb * 128 + row < active) {
            uint4v v = *(const uint4v*)&lds[row * 136 + c8 * 8];
            *(uint4v*)&hbuf[(size_t)(hbase + rb * 128 + row) * HD + blockIdx.x * 128 + c8 * 8] = v;
        }
    }
}

// ---------------- MFMA GEMM2: y = h @ Wd, f32 out with fused combine.
// A and B both via global_load_lds (all-bf16 operands).
__global__ __launch_bounds__(256) void gemm2_mfma(
    const u16* __restrict__ hbuf, const u16* __restrict__ Wd,
    float* __restrict__ out,
    const int* __restrict__ cnt, const int* __restrict__ tokmap,
    const float* __restrict__ invw, int bucketBase)
{
    int z = blockIdx.z;
    int bucket = (bucketBase < 0) ? -1 : (bucketBase + z);
    int active = (bucket < 0) ? T_TOK : cnt[bucket];
    int rb = blockIdx.y;
    if (rb * 128 >= active) return;
    int tid = threadIdx.x;
    int hbase = z * 8192;

    int r = tid & 127;
    int h = tid >> 7;
    int grow = rb * 128 + r;
    int srow = (grow < active) ? grow : (active - 1);
    const u16* aptr = hbuf + (size_t)(hbase + srow) * HD + h * 8;
    size_t woff = (size_t)(blockIdx.x * 128 + r) * HD + h * 8;
    const u16* w0p = Wd + woff;

    __shared__ short lds[8192];    // staging A/B (2x4096 shorts)
    short* ldsA  = lds;
    short* ldsB0 = lds + 4096;

    f32x4 acc[4][4];
#pragma unroll
    for (int i = 0; i < 4; i++)
#pragma unroll
        for (int j = 0; j < 4; j++) acc[i][j] = (f32x4){0.f, 0.f, 0.f, 0.f};

    int lane = tid & 63;
    int wid = tid >> 6;
    int wm = (wid >> 1) * 64, wn = (wid & 1) * 64;
    int lg = lane >> 4, lm = lane & 15;

    for (int kk = 0; kk < 32; ++kk) {
        __syncthreads();
#pragma unroll
        for (int q = 0; q < 2; q++) {
            gload16(aptr + kk * 32 + q * 16, &ldsA[(size_t)(q * 256 + wid * 64) * 8]);
            gload16(w0p + kk * 32 + q * 16, &ldsB0[(size_t)(q * 256 + wid * 64) * 8]);
        }
        __syncthreads();
        short8v afr[4], b0f[4];
#pragma unroll
        for (int f = 0; f < 4; f++) {
            afr[f] = *(const short8v*)&ldsA[(size_t)(lg * 128 + wm + f * 16 + lm) * 8];
            b0f[f] = *(const short8v*)&ldsB0[(size_t)(lg * 128 + wn + f * 16 + lm) * 8];
        }
#pragma unroll
        for (int i = 0; i < 4; i++)
#pragma unroll
            for (int j = 0; j < 4; j++)
                acc[i][j] = __builtin_amdgcn_mfma_f32_16x16x32_bf16(afr[i], b0f[j], acc[i][j], 0, 0, 0);
    }

    // epilogue: direct f32 stores (16-lane 64B segments)
#pragma unroll
    for (int i = 0; i < 4; i++)
#pragma unroll
        for (int rr = 0; rr < 4; rr++) {
            int m = wm + i * 16 + (lane >> 4) * 4 + rr;
            int s = rb * 128 + m;
            if (s < active) {
                if (bucket < 0) {
                    size_t rowOff = (size_t)s * HD + blockIdx.x * 128;
#pragma unroll
                    for (int j = 0; j < 4; j++)
                        out[rowOff + wn + j * 16 + lm] = acc[i][j][rr];
                } else {
                    int t = tokmap[bucket * T_TOK + s];
                    float w = SCALE_F * invw[t * 2 + (bucket & 1)];
                    size_t rowOff = (size_t)t * HD + blockIdx.x * 128;
#pragma unroll
                    for (int j = 0; j < 4; j++)
                        out[rowOff + wn + j * 16 + lm] += w * acc[i][j][rr];
                }
            }
        }
}

extern "C" void kernel_launch(void* const* d_in, const int* in_sizes, int n_in,
                              void* d_out, int out_size, void* d_ws, size_t ws_size,
                              hipStream_t stream) {
    float* out  = (float*)d_out;
    float* lout = out + (size_t)T_TOK * HD;

    if (out_size != OUT_ELEMS) {
        diag_kernel<<<dim3((out_size + 255) / 256), 256, 0, stream>>>(out, out_size, 230.f);
        return;
    }
    const int SZ_X = T_TOK * HD, SZ_R = HD * NE, SZ_S = MAT_ELEMS, SZ_E = NE * MAT_ELEMS;
    const int dictSig[8] = {SZ_X, SZ_R, SZ_S, SZ_S, SZ_S, SZ_E, SZ_E, SZ_E};
    const int alphSig[8] = {SZ_X, SZ_E, SZ_E, SZ_R, SZ_S, SZ_S, SZ_S, SZ_E};
    bool isDict = (n_in == 8), isAlph = (n_in == 8);
    for (int i = 0; i < 8 && n_in == 8; i++) {
        if (in_sizes[i] != dictSig[i]) isDict = false;
        if (in_sizes[i] != alphSig[i]) isAlph = false;
    }
    const void *X, *Wr, *shg, *shu, *shd, *wg, *wu, *wd;
    if (isDict) {
        X = d_in[0]; Wr = d_in[1]; shg = d_in[2]; shu = d_in[3]; shd = d_in[4];
        wg = d_in[5]; wu = d_in[6]; wd = d_in[7];
    } else if (isAlph) {
        X = d_in[0]; wd = d_in[1]; wg = d_in[2]; Wr = d_in[3];
        shd = d_in[4]; shg = d_in[5]; shu = d_in[6]; wu = d_in[7];
    } else {
        diag_kernel<<<dim3((out_size + 255) / 256), 256, 0, stream>>>(out, out_size, 240.f);
        return;
    }
    if (ws_size < WS_NEED) {
        diag_kernel<<<dim3((out_size + 255) / 256), 256, 0, stream>>>(
            out, out_size, (float)(ws_size >> 20));
        return;
    }

    char* ws = (char*)d_ws;
    int*   flag   = (int*)(ws + WS_FLAG);
    int*   cnt    = (int*)(ws + WS_CNT);
    float* invw   = (float*)(ws + WS_INVW);
    u32*   picks  = (u32*)(ws + WS_PICKS);
    int*   tokmap = (int*)(ws + WS_TOKMAP);
    u16*   wT     = (u16*)(ws + WS_WT);       // rotating: gate^T, up^T, down^T (bf16)
    u16*   hbuf   = (u16*)(ws + WS_HBUF);     // [16384][1024] bf16
    u16*   wTg = wT, *wTu = wT + MAT_ELEMS, *wTd = wT + 2ull * MAT_ELEMS;

    detect_kernel<<<dim3(1), 64, 0, stream>>>((const u16*)Wr, flag);
    router_kernel<<<dim3(T_TOK / 4), 256, 0, stream>>>(X, Wr, flag, lout, picks, invw);
    compact_kernel<<<dim3(NB), 256, 0, stream>>>(picks, cnt, tokmap);

    // shared expert: out = swiglu(X) over all T rows
    transpose3_kernel<<<dim3(16, 16, 3), 256, 0, stream>>>(shg, shu, shd, 0, flag, wT);
    gemm1_mfma<<<dim3(8, 128, 1), 256, 0, stream>>>(X, wTg, wTu, hbuf, cnt, tokmap, flag, -1);
    gemm2_mfma<<<dim3(8, 128, 1), 256, 0, stream>>>(hbuf, wTd, out, cnt, tokmap, invw, -1);

    // routed experts: rotate weights; z = k-bucket (2 per expert); out += w*y
    for (int e = 0; e < NE; e++) {
        transpose3_kernel<<<dim3(16, 16, 3), 256, 0, stream>>>(wg, wu, wd, e, flag, wT);
        gemm1_mfma<<<dim3(8, 64, 2), 256, 0, stream>>>(X, wTg, wTu, hbuf, cnt, tokmap, flag, e * 2);
        gemm2_mfma<<<dim3(8, 64, 2), 256, 0, stream>>>(hbuf, wTd, out, cnt, tokmap, invw, e * 2);
    }
}

// Round 16
// 1320.107 us; speedup vs baseline: 8.1101x; 1.0657x over previous
//
#include <hip/hip_runtime.h>
#include <hip/hip_bf16.h>

typedef unsigned short u16;
typedef unsigned int u32;
typedef __attribute__((ext_vector_type(8))) short short8v;   // 8 bf16 = 16B MFMA A/B frag
typedef __attribute__((ext_vector_type(4))) float f32x4;
typedef __attribute__((ext_vector_type(4))) u32 uint4v;      // 16B

#define T_TOK 16384
#define HD 1024
#define NE 8
#define NB 16
#define MAT_ELEMS (1024*1024)
#define SCALE_F 1.0f
#define OUT_ELEMS (T_TOK*HD + T_TOK*NE)

// ws layout (39.2 MiB total; proven ws_size >= 49.4 MiB from round-7 guard)
#define WS_FLAG    0
#define WS_CNT     256
#define WS_INVW    512                        // [T][2] f32
#define WS_PICKS   131584                     // [T] u32 (e1 | e2<<8)
#define WS_TOKMAP  197120                     // [16][T] int
#define WS_WT      1245696                    // 3 x 1M bf16 (gate^T, up^T, down^T)
#define WS_HBUF    7537152                    // [16384][1024] bf16
#define WS_NEED    41091584ull

typedef const __attribute__((address_space(1))) u32* gas_ptr;
typedef __attribute__((address_space(3))) u32* las_ptr;

__device__ __forceinline__ void gload16(const void* g, void* l) {
    __builtin_amdgcn_global_load_lds((gas_ptr)g, (las_ptr)l, 16, 0, 0);
}

__device__ __forceinline__ float bf2f(u16 u) {
    union { u32 i; float f; } v; v.i = ((u32)u) << 16; return v.f;
}
__device__ __forceinline__ u16 f2bf(float f) {
    __hip_bfloat16 h = __float2bfloat16(f);
    return *reinterpret_cast<u16*>(&h);
}

__global__ __launch_bounds__(256) void diag_kernel(float* __restrict__ out, int n, float v)
{
    int i = blockIdx.x * 256 + threadIdx.x;
    if (i < n) out[i] = v;
}

// dtype detector on w_router's first 256 u16s (1 = f32, 0 = bf16)
__global__ void detect_kernel(const u16* __restrict__ wr, int* __restrict__ flag)
{
    int lane = threadIdx.x & 63;
    int sane = 0;
#pragma unroll
    for (int q = 0; q < 4; q++) {
        u16 u = wr[lane * 4 + q];
        int e = (u >> 7) & 0xFF;
        if ((e >= 100 && e <= 140) || u == 0) sane++;
    }
#pragma unroll
    for (int off = 32; off; off >>= 1) sane += __shfl_xor(sane, off);
    if (lane == 0) *flag = (sane < 210) ? 1 : 0;
}

// ---------------- router phase 1: per-token math; NO atomics.
__global__ __launch_bounds__(256) void router_kernel(
    const void* __restrict__ Xraw, const void* __restrict__ Wraw,
    const int* __restrict__ flag,
    float* __restrict__ Lout, u32* __restrict__ picks, float* __restrict__ invw)
{
    int t = blockIdx.x * 4 + (threadIdx.x >> 6);
    int lane = threadIdx.x & 63;
    bool isf32 = (*flag != 0);
    float xv[16];
    if (isf32) {
        const float* xr = (const float*)Xraw + (size_t)t * HD + lane * 16;
#pragma unroll
        for (int q = 0; q < 4; q++) {
            f32x4 v = *(const f32x4*)(xr + q * 4);
#pragma unroll
            for (int j = 0; j < 4; j++) xv[q * 4 + j] = v[j];
        }
    } else {
        const u16* xr = (const u16*)Xraw + (size_t)t * HD + lane * 16;
#pragma unroll
        for (int q = 0; q < 2; q++) {
            uint4v v = *(const uint4v*)(xr + q * 8);
            const u16* p = (const u16*)&v;
#pragma unroll
            for (int j = 0; j < 8; j++) xv[q * 8 + j] = bf2f(p[j]);
        }
    }
    float acc[NE];
#pragma unroll
    for (int e = 0; e < NE; e++) acc[e] = 0.f;
#pragma unroll
    for (int j = 0; j < 16; j++) {
        float wr[NE];
        if (isf32) {
            const float* w = (const float*)Wraw + (size_t)(lane * 16 + j) * NE;
            f32x4 a = *(const f32x4*)w, b = *(const f32x4*)(w + 4);
#pragma unroll
            for (int e = 0; e < 4; e++) { wr[e] = a[e]; wr[4 + e] = b[e]; }
        } else {
            uint4v v = *(const uint4v*)((const u16*)Wraw + (size_t)(lane * 16 + j) * NE);
            const u16* p = (const u16*)&v;
#pragma unroll
            for (int e = 0; e < NE; e++) wr[e] = bf2f(p[e]);
        }
#pragma unroll
        for (int e = 0; e < NE; e++) acc[e] += xv[j] * wr[e];
    }
#pragma unroll
    for (int off = 32; off; off >>= 1)
#pragma unroll
        for (int e = 0; e < NE; e++) acc[e] += __shfl_xor(acc[e], off);

    if (lane == 0) {
        float mx = acc[0];
#pragma unroll
        for (int e = 1; e < NE; e++) mx = fmaxf(mx, acc[e]);
        float p[NE], sum = 0.f;
#pragma unroll
        for (int e = 0; e < NE; e++) { p[e] = expf(acc[e] - mx); sum += p[e]; }
        float inv = 1.f / sum;
#pragma unroll
        for (int e = 0; e < NE; e++) p[e] *= inv;
        int i1 = 0;
#pragma unroll
        for (int e = 1; e < NE; e++) if (p[e] > p[i1]) i1 = e;
        int i2 = (i1 == 0) ? 1 : 0;
#pragma unroll
        for (int e = 0; e < NE; e++) { if (e == i1 || e == i2) continue; if (p[e] > p[i2]) i2 = e; }
        *(f32x4*)&Lout[(size_t)t * NE]     = (f32x4){acc[0], acc[1], acc[2], acc[3]};
        *(f32x4*)&Lout[(size_t)t * NE + 4] = (f32x4){acc[4], acc[5], acc[6], acc[7]};
        picks[t] = (u32)i1 | ((u32)i2 << 8);
        invw[t * 2 + 0] = p[i1];
        invw[t * 2 + 1] = p[i2];
    }
}

// ---------------- router phase 2: deterministic stable compaction, 1 block per bucket
__global__ __launch_bounds__(256) void compact_kernel(
    const u32* __restrict__ picks, int* __restrict__ cnt, int* __restrict__ tokmap)
{
    __shared__ int wtot[4];
    int b = blockIdx.x;
    int e = b >> 1;
    bool k1 = (b & 1) != 0;
    int tid = threadIdx.x, lane = tid & 63, wid = tid >> 6;
    int base = 0;
    for (int t0 = 0; t0 < T_TOK; t0 += 256) {
        int t = t0 + tid;
        u32 pk = picks[t];
        int pe = k1 ? (int)((pk >> 8) & 0xFF) : (int)(pk & 0xFF);
        bool f = (pe == e);
        unsigned long long m = __ballot(f);
        int off = (int)__popcll(m & ((1ull << lane) - 1ull));
        if (lane == 0) wtot[wid] = (int)__popcll(m);
        __syncthreads();
        int wbase = 0;
#pragma unroll
        for (int w = 0; w < 4; w++) wbase += (w < wid) ? wtot[w] : 0;
        int tot = wtot[0] + wtot[1] + wtot[2] + wtot[3];
        if (f) tokmap[b * T_TOK + base + wbase + off] = t;
        base += tot;
        __syncthreads();
    }
    if (tid == 0) cnt[b] = base;
}

// ---------------- transpose+convert one expert's 3 matrices -> wT [n][k] bf16
__global__ __launch_bounds__(256) void transpose3_kernel(
    const void* __restrict__ gsrc, const void* __restrict__ usrc, const void* __restrict__ dsrc,
    int expertIdx, const int* __restrict__ flag,
    u16* __restrict__ wT)
{
    __shared__ u16 tile[64][66];
    int z = blockIdx.z;
    const void* srcv = (z == 0) ? gsrc : (z == 1) ? usrc : dsrc;
    size_t base = (size_t)expertIdx * MAT_ELEMS;
    u16* dst = wT + (size_t)z * MAT_ELEMS;
    int h0 = blockIdx.x * 64;
    int n0 = blockIdx.y * 64;
    int tid = threadIdx.x;
    bool isf32 = (*flag != 0);
#pragma unroll
    for (int i = 0; i < 2; i++) {
        int v = tid + i * 256;
        int row = v >> 3, c8 = v & 7;
        size_t idx = base + (size_t)(h0 + row) * HD + n0 + c8 * 8;
        u16 pv[8];
        if (isf32) {
            const float* s = (const float*)srcv + idx;
            f32x4 a = *(const f32x4*)s;
            f32x4 b = *(const f32x4*)(s + 4);
#pragma unroll
            for (int j = 0; j < 4; j++) { pv[j] = f2bf(a[j]); pv[4 + j] = f2bf(b[j]); }
        } else {
            *(uint4v*)pv = *(const uint4v*)((const u16*)srcv + idx);
        }
#pragma unroll
        for (int j = 0; j < 8; j++) tile[c8 * 8 + j][row] = pv[j];
    }
    __syncthreads();
#pragma unroll
    for (int i = 0; i < 2; i++) {
        int v = tid + i * 256;
        int row = v >> 3, c8 = v & 7;
        u16 pv[8];
#pragma unroll
        for (int j = 0; j < 8; j++) pv[j] = tile[row][c8 * 8 + j];
        *(uint4v*)&dst[(size_t)(n0 + row) * HD + h0 + c8 * 8] = *(uint4v*)pv;
    }
}

// XCD-aware block mapping: flat -> (bx, rb). Each XCD (flat%8) gets a
// y-contiguous chunk covering ALL column blocks -> A-tiles L2-local per XCD.
__device__ __forceinline__ bool swz_map(int flat, int ny, int& bx, int& rb)
{
    if (flat >= ny * 8) return false;
    int l = (flat & 7) * ny + (flat >> 3);   // logical tile index, x-fastest
    bx = l & 7;
    rb = l >> 3;
    return true;
}

// ---------------- MFMA GEMM1: h = silu(X@Wg)*(X@Wu) -> hbuf (bf16, compacted rows)
// A: reg-staged f32->bf16 cvt (prefetch under MFMA). B0/B1: global_load_lds width 16.
__global__ __launch_bounds__(256) void gemm1_mfma(
    const void* __restrict__ Xraw,
    const u16* __restrict__ Wg, const u16* __restrict__ Wu,
    u16* __restrict__ hbuf,
    const int* __restrict__ cnt, const int* __restrict__ tokmap,
    const int* __restrict__ flag, int bucketBase)
{
    int z = blockIdx.z;
    int bucket = (bucketBase < 0) ? -1 : (bucketBase + z);
    int active = (bucket < 0) ? T_TOK : cnt[bucket];
    int ny = (active + 127) >> 7;
    if (bucket >= 0 && ny > 64) ny = 64;      // hbuf capacity cap (8192 rows/bucket)
    int bx, rb;
    if (!swz_map(blockIdx.x, ny, bx, rb)) return;
    int tid = threadIdx.x;
    bool isf32 = (*flag != 0);
    int hbase = z * 8192;

    int r = tid & 127;
    int h = tid >> 7;                        // k-half (0/1)
    int grow = rb * 128 + r;
    int srow = (grow < active) ? grow : (active - 1);
    size_t arow = (bucket < 0) ? (size_t)srow : (size_t)tokmap[bucket * T_TOK + srow];

    const float* af = (const float*)Xraw + arow * HD + h * 8;
    const u16*   ab = (const u16*)Xraw + arow * HD + h * 8;
    size_t woff = (size_t)(bx * 128 + r) * HD + h * 8;
    const u16* w0p = Wg + woff;
    const u16* w1p = Wu + woff;

    __shared__ short lds[17408];   // staging A/B0/B1 (3x4096 shorts); epilogue 128x136
    short* ldsA  = lds;
    short* ldsB0 = lds + 4096;
    short* ldsB1 = lds + 8192;

    f32x4 acc0[4][4], acc1[4][4];
#pragma unroll
    for (int i = 0; i < 4; i++)
#pragma unroll
        for (int j = 0; j < 4; j++) {
            acc0[i][j] = (f32x4){0.f, 0.f, 0.f, 0.f};
            acc1[i][j] = (f32x4){0.f, 0.f, 0.f, 0.f};
        }

    int lane = tid & 63;
    int wid = tid >> 6;
    int wm = (wid >> 1) * 64, wn = (wid & 1) * 64;
    int lg = lane >> 4, lm = lane & 15;

    auto loadA = [&](int ko) -> uint4v {
        if (isf32) {
            f32x4 x0 = *(const f32x4*)(af + ko);
            f32x4 x1 = *(const f32x4*)(af + ko + 4);
            u16 t[8];
#pragma unroll
            for (int j = 0; j < 4; j++) { t[j] = f2bf(x0[j]); t[4 + j] = f2bf(x1[j]); }
            return *(uint4v*)t;
        }
        return *(const uint4v*)(ab + ko);
    };

    uint4v ra[2];
#pragma unroll
    for (int q = 0; q < 2; q++) ra[q] = loadA(q * 16);

    for (int kk = 0; kk < 32; ++kk) {
        __syncthreads();                          // LDS free from prev compute
#pragma unroll
        for (int q = 0; q < 2; q++) {
            *(uint4v*)&ldsA[(size_t)(q * 256 + tid) * 8] = ra[q];
            gload16(w0p + kk * 32 + q * 16, &ldsB0[(size_t)(q * 256 + wid * 64) * 8]);
            gload16(w1p + kk * 32 + q * 16, &ldsB1[(size_t)(q * 256 + wid * 64) * 8]);
        }
        __syncthreads();                          // vmcnt(0): B landed, A written
        if (kk + 1 < 32) {                        // A-prefetch hides under MFMA
#pragma unroll
            for (int q = 0; q < 2; q++) ra[q] = loadA((kk + 1) * 32 + q * 16);
        }
        short8v afr[4], b0f[4], b1f[4];
#pragma unroll
        for (int f = 0; f < 4; f++) {
            afr[f] = *(const short8v*)&ldsA[(size_t)(lg * 128 + wm + f * 16 + lm) * 8];
            b0f[f] = *(const short8v*)&ldsB0[(size_t)(lg * 128 + wn + f * 16 + lm) * 8];
            b1f[f] = *(const short8v*)&ldsB1[(size_t)(lg * 128 + wn + f * 16 + lm) * 8];
        }
#pragma unroll
        for (int i = 0; i < 4; i++)
#pragma unroll
            for (int j = 0; j < 4; j++) {
                acc0[i][j] = __builtin_amdgcn_mfma_f32_16x16x32_bf16(afr[i], b0f[j], acc0[i][j], 0, 0, 0);
                acc1[i][j] = __builtin_amdgcn_mfma_f32_16x16x32_bf16(afr[i], b1f[j], acc1[i][j], 0, 0, 0);
            }
    }

    __syncthreads();
#pragma unroll
    for (int i = 0; i < 4; i++)
#pragma unroll
        for (int j = 0; j < 4; j++)
#pragma unroll
            for (int rr = 0; rr < 4; rr++) {
                int m = wm + i * 16 + (lane >> 4) * 4 + rr;
                int n = wn + j * 16 + lm;
                float g = acc0[i][j][rr];
                float u = acc1[i][j][rr];
                float sg = g / (1.f + __expf(-g));    // silu
                lds[m * 136 + n] = (short)f2bf(sg * u);
            }
    __syncthreads();
#pragma unroll
    for (int i = 0; i < 8; i++) {
        int s0 = tid + i * 256;
        int row = s0 >> 4;
        int c8 = s0 & 15;
        if (rb * 128 + row < active) {
            uint4v v = *(const uint4v*)&lds[row * 136 + c8 * 8];
            *(uint4v*)&hbuf[(size_t)(hbase + rb * 128 + row) * HD + bx * 128 + c8 * 8] = v;
        }
    }
}

// ---------------- MFMA GEMM2: y = h @ Wd, f32 out with fused combine.
__global__ __launch_bounds__(256) void gemm2_mfma(
    const u16* __restrict__ hbuf, const u16* __restrict__ Wd,
    float* __restrict__ out,
    const int* __restrict__ cnt, const int* __restrict__ tokmap,
    const float* __restrict__ invw, int bucketBase)
{
    int z = blockIdx.z;
    int bucket = (bucketBase < 0) ? -1 : (bucketBase + z);
    int active = (bucket < 0) ? T_TOK : cnt[bucket];
    int ny = (active + 127) >> 7;
    if (bucket >= 0 && ny > 64) ny = 64;
    int bx, rb;
    if (!swz_map(blockIdx.x, ny, bx, rb)) return;
    int tid = threadIdx.x;
    int hbase = z * 8192;

    int r = tid & 127;
    int h = tid >> 7;
    int grow = rb * 128 + r;
    int srow = (grow < active) ? grow : (active - 1);
    const u16* aptr = hbuf + (size_t)(hbase + srow) * HD + h * 8;
    size_t woff = (size_t)(bx * 128 + r) * HD + h * 8;
    const u16* w0p = Wd + woff;

    __shared__ short lds[8192];    // staging A/B (2x4096 shorts)
    short* ldsA  = lds;
    short* ldsB0 = lds + 4096;

    f32x4 acc[4][4];
#pragma unroll
    for (int i = 0; i < 4; i++)
#pragma unroll
        for (int j = 0; j < 4; j++) acc[i][j] = (f32x4){0.f, 0.f, 0.f, 0.f};

    int lane = tid & 63;
    int wid = tid >> 6;
    int wm = (wid >> 1) * 64, wn = (wid & 1) * 64;
    int lg = lane >> 4, lm = lane & 15;

    for (int kk = 0; kk < 32; ++kk) {
        __syncthreads();
#pragma unroll
        for (int q = 0; q < 2; q++) {
            gload16(aptr + kk * 32 + q * 16, &ldsA[(size_t)(q * 256 + wid * 64) * 8]);
            gload16(w0p + kk * 32 + q * 16, &ldsB0[(size_t)(q * 256 + wid * 64) * 8]);
        }
        __syncthreads();
        short8v afr[4], b0f[4];
#pragma unroll
        for (int f = 0; f < 4; f++) {
            afr[f] = *(const short8v*)&ldsA[(size_t)(lg * 128 + wm + f * 16 + lm) * 8];
            b0f[f] = *(const short8v*)&ldsB0[(size_t)(lg * 128 + wn + f * 16 + lm) * 8];
        }
#pragma unroll
        for (int i = 0; i < 4; i++)
#pragma unroll
            for (int j = 0; j < 4; j++)
                acc[i][j] = __builtin_amdgcn_mfma_f32_16x16x32_bf16(afr[i], b0f[j], acc[i][j], 0, 0, 0);
    }

    // epilogue: direct f32 stores (16-lane 64B segments)
#pragma unroll
    for (int i = 0; i < 4; i++)
#pragma unroll
        for (int rr = 0; rr < 4; rr++) {
            int m = wm + i * 16 + (lane >> 4) * 4 + rr;
            int s = rb * 128 + m;
            if (s < active) {
                if (bucket < 0) {
                    size_t rowOff = (size_t)s * HD + bx * 128;
#pragma unroll
                    for (int j = 0; j < 4; j++)
                        out[rowOff + wn + j * 16 + lm] = acc[i][j][rr];
                } else {
                    int t = tokmap[bucket * T_TOK + s];
                    float w = SCALE_F * invw[t * 2 + (bucket & 1)];
                    size_t rowOff = (size_t)t * HD + bx * 128;
#pragma unroll
                    for (int j = 0; j < 4; j++)
                        out[rowOff + wn + j * 16 + lm] += w * acc[i][j][rr];
                }
            }
        }
}

extern "C" void kernel_launch(void* const* d_in, const int* in_sizes, int n_in,
                              void* d_out, int out_size, void* d_ws, size_t ws_size,
                              hipStream_t stream) {
    float* out  = (float*)d_out;
    float* lout = out + (size_t)T_TOK * HD;

    if (out_size != OUT_ELEMS) {
        diag_kernel<<<dim3((out_size + 255) / 256), 256, 0, stream>>>(out, out_size, 230.f);
        return;
    }
    const int SZ_X = T_TOK * HD, SZ_R = HD * NE, SZ_S = MAT_ELEMS, SZ_E = NE * MAT_ELEMS;
    const int dictSig[8] = {SZ_X, SZ_R, SZ_S, SZ_S, SZ_S, SZ_E, SZ_E, SZ_E};
    const int alphSig[8] = {SZ_X, SZ_E, SZ_E, SZ_R, SZ_S, SZ_S, SZ_S, SZ_E};
    bool isDict = (n_in == 8), isAlph = (n_in == 8);
    for (int i = 0; i < 8 && n_in == 8; i++) {
        if (in_sizes[i] != dictSig[i]) isDict = false;
        if (in_sizes[i] != alphSig[i]) isAlph = false;
    }
    const void *X, *Wr, *shg, *shu, *shd, *wg, *wu, *wd;
    if (isDict) {
        X = d_in[0]; Wr = d_in[1]; shg = d_in[2]; shu = d_in[3]; shd = d_in[4];
        wg = d_in[5]; wu = d_in[6]; wd = d_in[7];
    } else if (isAlph) {
        X = d_in[0]; wd = d_in[1]; wg = d_in[2]; Wr = d_in[3];
        shd = d_in[4]; shg = d_in[5]; shu = d_in[6]; wu = d_in[7];
    } else {
        diag_kernel<<<dim3((out_size + 255) / 256), 256, 0, stream>>>(out, out_size, 240.f);
        return;
    }
    if (ws_size < WS_NEED) {
        diag_kernel<<<dim3((out_size + 255) / 256), 256, 0, stream>>>(
            out, out_size, (float)(ws_size >> 20));
        return;
    }

    char* ws = (char*)d_ws;
    int*   flag   = (int*)(ws + WS_FLAG);
    int*   cnt    = (int*)(ws + WS_CNT);
    float* invw   = (float*)(ws + WS_INVW);
    u32*   picks  = (u32*)(ws + WS_PICKS);
    int*   tokmap = (int*)(ws + WS_TOKMAP);
    u16*   wT     = (u16*)(ws + WS_WT);       // rotating: gate^T, up^T, down^T (bf16)
    u16*   hbuf   = (u16*)(ws + WS_HBUF);     // [16384][1024] bf16
    u16*   wTg = wT, *wTu = wT + MAT_ELEMS, *wTd = wT + 2ull * MAT_ELEMS;

    detect_kernel<<<dim3(1), 64, 0, stream>>>((const u16*)Wr, flag);
    router_kernel<<<dim3(T_TOK / 4), 256, 0, stream>>>(X, Wr, flag, lout, picks, invw);
    compact_kernel<<<dim3(NB), 256, 0, stream>>>(picks, cnt, tokmap);

    // shared expert: out = swiglu(X) over all T rows (flat swizzled grid: 8*128)
    transpose3_kernel<<<dim3(16, 16, 3), 256, 0, stream>>>(shg, shu, shd, 0, flag, wT);
    gemm1_mfma<<<dim3(1024, 1, 1), 256, 0, stream>>>(X, wTg, wTu, hbuf, cnt, tokmap, flag, -1);
    gemm2_mfma<<<dim3(1024, 1, 1), 256, 0, stream>>>(hbuf, wTd, out, cnt, tokmap, invw, -1);

    // routed experts: rotate weights; z = k-bucket (2 per expert); out += w*y
    // flat swizzled grid 8*64 worst case; excess blocks exit on runtime ny
    for (int e = 0; e < NE; e++) {
        transpose3_kernel<<<dim3(16, 16, 3), 256, 0, stream>>>(wg, wu, wd, e, flag, wT);
        gemm1_mfma<<<dim3(512, 1, 2), 256, 0, stream>>>(X, wTg, wTu, hbuf, cnt, tokmap, flag, e * 2);
        gemm2_mfma<<<dim3(512, 1, 2), 256, 0, stream>>>(hbuf, wTd, out, cnt, tokmap, invw, e * 2);
    }
}